// Round 6
// baseline (329.883 us; speedup 1.0000x reference)
//
#include <hip/hip_runtime.h>

// Problem constants
#define Cn   192      // channels = 3*D
#define Dn   64       // hidden
#define G3   192      // 3*D gates
#define HWn  16384    // H*W per batch
#define NSp  131072L  // B*H*W total spatial
#define Tn   128

typedef unsigned short u16;
typedef __attribute__((ext_vector_type(8))) short s8v;   // 8 bf16 (4 VGPRs) MFMA A/B frag
typedef __attribute__((ext_vector_type(4))) float f4v;   // MFMA C/D frag

__device__ __forceinline__ float bf2f(u16 u){
  union { unsigned int i; float f; } v; v.i = ((unsigned int)u) << 16; return v.f;
}
__device__ __forceinline__ u16 f2bf(float f){
  union { float f; unsigned int u; } v; v.f = f;
  return (u16)((v.u + 0x7FFFu + ((v.u >> 16) & 1u)) >> 16);  // RNE
}
__device__ __forceinline__ s8v load8_f32_as_bf16(const float* __restrict__ p){
  s8v r;
  #pragma unroll
  for (int i = 0; i < 8; i++) r[i] = (short)f2bf(p[i]);
  return r;
}
// fast transcendentals
__device__ __forceinline__ float ex2f(float x){
#if __has_builtin(__builtin_amdgcn_exp2f)
  return __builtin_amdgcn_exp2f(x);
#else
  float r; asm("v_exp_f32 %0, %1" : "=v"(r) : "v"(x)); return r;
#endif
}
__device__ __forceinline__ float rcpa(float x){
#if __has_builtin(__builtin_amdgcn_rcpf)
  return __builtin_amdgcn_rcpf(x);
#else
  float r; asm("v_rcp_f32 %0, %1" : "=v"(r) : "v"(x)); return r;
#endif
}
__device__ __forceinline__ unsigned int pk2bf(float a, float b){
  unsigned int r; asm("v_cvt_pk_bf16_f32 %0, %1, %2" : "=v"(r) : "v"(a), "v"(b)); return r;
}

// gate-group scale folded into weights: r,z: -log2(e)  (sigmoid(x)=rcp(1+exp2(-log2e*x)))
//                                       n:   -2log2(e) (tanh(y)=2*rcp(1+exp2(-2log2e*y))-1)
#define SC_RZ (-1.4426950408889634f)
#define SC_N  (-2.8853900817779268f)

// G layout (interleaved for scan locality): per spatial s, 16 d-quads x 3 gate
// groups x 4: element offset = s*192 + dq*12 + g3*4 + r, where d = 4*dq + r.

// ---------------------------------------------------------------------------
// Kernel 0: W_comb = W_ih @ Wi (bf16, gate-scaled); b_comb = W_ih@bi + b_ih
// (+ b_hh for r,z gates — n's b_hh sits inside r*(.) and cannot fold), scaled.
// ---------------------------------------------------------------------------
__global__ __launch_bounds__(256) void k_wcomb(const float* __restrict__ Wi, const float* __restrict__ bi,
                                               const float* __restrict__ W_ih, const float* __restrict__ b_ih,
                                               const float* __restrict__ b_hh,
                                               u16* __restrict__ wcomb, float* __restrict__ bcomb){
  if (blockIdx.x < 144) {
    int idx = blockIdx.x * 256 + threadIdx.x;   // 36864 = 192*192
    int g = idx / 192, c = idx - g * 192;
    float acc = 0.f;
    #pragma unroll 8
    for (int d = 0; d < 64; d++)
      acc += W_ih[g * 64 + d] * Wi[d * 192 + c];
    float sc = (g >= 128) ? SC_N : SC_RZ;
    wcomb[g * 192 + c] = f2bf(sc * acc);
  } else if (threadIdx.x < 192) {
    int g = threadIdx.x;
    float acc = b_ih[g];
    for (int d = 0; d < 64; d++)
      acc += W_ih[g * 64 + d] * bi[d];
    if (g < 128) acc += b_hh[g];          // fold r,z hidden-bias into the x-gate stream
    float sc = (g >= 128) ? SC_N : SC_RZ;
    bcomb[g] = sc * acc;
  }
}

// ---------------------------------------------------------------------------
// Kernel 1: G = x @ W_comb^T + b_comb  (bf16, pre-scaled, interleaved layout).
// Staging rewritten: 4ch x 4sp per thread, cvt_pk pack, ds_write_b64 with an
// 8-channel-block XOR swizzle (c ^= ((s>>2)&3)<<3) -> 2-way banks (was 48
// scalar 2B writes on 2 banks = 8-way). Read applies the same XOR (involution).
// ---------------------------------------------------------------------------
__global__ __launch_bounds__(256) void k_gates(const float* __restrict__ x, const u16* __restrict__ wcomb,
                                               const float* __restrict__ bcomb, u16* __restrict__ G){
  __shared__ u16 xT[64][200];                 // [spatial][channel], row 400 B
  const int tid = threadIdx.x;
  const int wave = tid >> 6, lane = tid & 63;
  const int col = lane & 15, kq = lane >> 4;
  const long s0 = (long)blockIdx.x * 64;
  const int b   = (int)(s0 >> 14);
  const int hw0 = (int)(s0 & 16383);
  const int dq  = 4 * wave + kq;              // this lane's d-quad (d = 4dq..4dq+3)
  const int cswz = (col >> 2) << 3;           // read-side XOR (s = nt*16+col -> (s>>2)&3 = col>>2)

  // A-frags: gate rows g = g3*64 + 16*wave + col; k = kc*32 + kq*8 + i (standard)
  s8v afrag[3][6];
  f4v biasv[3];
  #pragma unroll
  for (int g3 = 0; g3 < 3; g3++) {
    int g = g3 * 64 + 16 * wave + col;
    #pragma unroll
    for (int kc = 0; kc < 6; kc++)
      afrag[g3][kc] = *(const s8v*)(wcomb + g * 192 + kc * 32 + kq * 8);
    biasv[g3] = *(const f4v*)(bcomb + g3 * 64 + 16 * wave + 4 * kq);
  }

  // Stage x tile transposed: 4 channels x 4 spatial per work item
  const float* xb = x + (long)b * 192 * HWn + hw0;
  for (int idx = tid; idx < 768; idx += 256) {
    int c  = (idx >> 4) * 4;
    int s4 = (idx & 15) * 4;
    f4v v0 = *(const f4v*)(xb + (long)(c + 0) * HWn + s4);
    f4v v1 = *(const f4v*)(xb + (long)(c + 1) * HWn + s4);
    f4v v2 = *(const f4v*)(xb + (long)(c + 2) * HWn + s4);
    f4v v3 = *(const f4v*)(xb + (long)(c + 3) * HWn + s4);
    #pragma unroll
    for (int j = 0; j < 4; j++) {
      int s  = s4 + j;
      int cS = c ^ (((s >> 2) & 3) << 3);
      uint2 wv;
      wv.x = pk2bf(v0[j], v1[j]);
      wv.y = pk2bf(v2[j], v3[j]);
      *(uint2*)(&xT[s][cS]) = wv;
    }
  }
  __syncthreads();

  f4v acc[4][3];
  #pragma unroll
  for (int nt = 0; nt < 4; nt++)
    #pragma unroll
    for (int g3 = 0; g3 < 3; g3++) acc[nt][g3] = biasv[g3];

  #pragma unroll
  for (int kc = 0; kc < 6; kc++) {
    #pragma unroll
    for (int nt = 0; nt < 4; nt++) {
      s8v bx = *(const s8v*)(&xT[nt * 16 + col][(kc * 32 + kq * 8) ^ cswz]);
      #pragma unroll
      for (int g3 = 0; g3 < 3; g3++)
        acc[nt][g3] = __builtin_amdgcn_mfma_f32_16x16x32_bf16(afrag[g3][kc], bx, acc[nt][g3], 0, 0, 0);
    }
  }

  // Epilogue: D rows = gates (4kq+r within tile), col = spatial -> uint2 stores
  #pragma unroll
  for (int nt = 0; nt < 4; nt++) {
    long sRow = (s0 + nt * 16 + col) * 192 + dq * 12;
    #pragma unroll
    for (int g3 = 0; g3 < 3; g3++) {
      uint2 wv;
      wv.x = pk2bf(acc[nt][g3][0], acc[nt][g3][1]);
      wv.y = pk2bf(acc[nt][g3][2], acc[nt][g3][3]);
      *(uint2*)(G + sRow + g3 * 4) = wv;
    }
  }
}

// ---------------------------------------------------------------------------
// Kernel 2: directional GRU scans — 4-wave d-split, raw-barrier double buffer,
// ping-pong 2x unroll (static LDS buffer index, zero rotate movs: prefetch
// writes into the just-consumed register set), deferred Hall store (h(t)
// stored at step t+1's head, off the dependent tail), merged z/n reciprocal
// (5 trans/h instead of 6).
// ---------------------------------------------------------------------------
__global__ __launch_bounds__(256) void k_scan(const u16* __restrict__ G, const float* __restrict__ W_hh,
                                              const float* __restrict__ b_hh, u16* __restrict__ Hall){
  __shared__ u16 ha[2][16][72];   // [buf][seq][d], row 144 B (16B-aligned)
  const int tid = threadIdx.x;
  const int w = tid >> 6, lane = tid & 63;
  const int col = lane & 15, kq = lane >> 4;
  const int dir  = blockIdx.x >> 6;   // 0:right 1:down 2:left 3:up
  const int sblk = blockIdx.x & 63;
  const int doff = 16 * w + 4 * kq;   // this lane's 4 d values
  const int dq   = 4 * w + kq;

  // A-frags: W_hh rows g = g3*64 + 16w + col, standard k order, gate-scaled
  s8v afrag[3][2];
  #pragma unroll
  for (int g3 = 0; g3 < 3; g3++) {
    float sc = (g3 == 2) ? SC_N : SC_RZ;
    const float* wr = W_hh + (g3 * 64 + 16 * w + col) * 64;
    #pragma unroll
    for (int kc = 0; kc < 2; kc++) {
      s8v f;
      #pragma unroll
      for (int i = 0; i < 8; i++) f[i] = (short)f2bf(sc * wr[kc * 32 + kq * 8 + i]);
      afrag[g3][kc] = f;
    }
  }
  // n-gate hidden bias in accumulator init (r,z b_hh folded into G)
  f4v biasn;
  {
    const float* bb = b_hh + 128 + doff;
    biasn = (f4v){SC_N * bb[0], SC_N * bb[1], SC_N * bb[2], SC_N * bb[3]};
  }

  const int seq = sblk * 16 + col;             // 0..1023
  const int b = seq >> 7, a = seq & 127;
  long base; int stride;
  if ((dir & 1) == 0) { base = ((long)(b * 128 + a)) * 128; stride = 1;   } // scan over w
  else                { base = (long)b * 16384 + a;         stride = 128; } // scan over h
  const int rev = dir >> 1;
  const long pd = rev ? -(long)stride : (long)stride;
  u16* __restrict__ Hs = Hall + (long)dir * (NSp * 64);
  const long pos0 = base + (long)(rev ? 127 : 0) * stride;
  const u16* gq = G  + pos0 * 192 + dq * 12;   // 24B contiguous (r,z,n) triple
  u16*       hq = Hs + pos0 * 64  + doff;

  for (int i = tid; i < 2 * 16 * 72; i += 256) ((u16*)ha)[i] = 0;   // h0 = 0

  float hold[4] = {0.f, 0.f, 0.f, 0.f};
  uint2 pwv = {0u, 0u};

  // depth-2 G prefetch: t=0 (set a) and t=1 (set b) in flight before the loop
  uint2 xra, xza, xna, xrb, xzb, xnb;
  xra = *(const uint2*)(gq); xza = *(const uint2*)(gq + 4); xna = *(const uint2*)(gq + 8);
  gq += pd * 192;
  xrb = *(const uint2*)(gq); xzb = *(const uint2*)(gq + 4); xnb = *(const uint2*)(gq + 8);
  __syncthreads();   // one full drain, before the loop only

  #define SCAN_STEP(P, XR, XZ, XN, T)                                              \
  do {                                                                             \
    s8v u0 = *(const s8v*)(&ha[(P)][col][kq * 8]);                                 \
    s8v u1 = *(const s8v*)(&ha[(P)][col][32 + kq * 8]);                            \
    if ((T) > 0) { *(uint2*)hq = pwv; hq += pd * 64; }   /* deferred h(t-1) */     \
    f4v acc0 = (f4v){0.f, 0.f, 0.f, 0.f};                                          \
    f4v acc1 = (f4v){0.f, 0.f, 0.f, 0.f};                                          \
    f4v acc2 = biasn;                                                              \
    acc0 = __builtin_amdgcn_mfma_f32_16x16x32_bf16(afrag[0][0], u0, acc0, 0, 0, 0);\
    acc1 = __builtin_amdgcn_mfma_f32_16x16x32_bf16(afrag[1][0], u0, acc1, 0, 0, 0);\
    acc2 = __builtin_amdgcn_mfma_f32_16x16x32_bf16(afrag[2][0], u0, acc2, 0, 0, 0);\
    acc0 = __builtin_amdgcn_mfma_f32_16x16x32_bf16(afrag[0][1], u1, acc0, 0, 0, 0);\
    acc1 = __builtin_amdgcn_mfma_f32_16x16x32_bf16(afrag[1][1], u1, acc1, 0, 0, 0);\
    acc2 = __builtin_amdgcn_mfma_f32_16x16x32_bf16(afrag[2][1], u1, acc2, 0, 0, 0);\
    const u16* pxr = (const u16*)&XR;                                              \
    const u16* pxz = (const u16*)&XZ;                                              \
    const u16* pxn = (const u16*)&XN;                                              \
    float hh[4];                                                                   \
    _Pragma("unroll")                                                              \
    for (int r = 0; r < 4; r++) {                                                  \
      float erv = ex2f(bf2f(pxr[r]) + acc0[r]);                                    \
      float rrv = rcpa(1.f + erv);                                                 \
      float ezv = ex2f(bf2f(pxz[r]) + acc1[r]);                                    \
      float dzv = 1.f + ezv;                                                       \
      float env = ex2f(bf2f(pxn[r]) + rrv * acc2[r]);                              \
      float dnv = 1.f + env;                                                       \
      float qv  = rcpa(dzv * dnv);      /* merged z,n reciprocal */                \
      float zzv = qv * dnv;             /* = 1/(1+ezv) */                          \
      float nnv = __builtin_fmaf(dzv + dzv, qv, -1.f);  /* = 2/(1+env)-1 */        \
      float h   = __builtin_fmaf(zzv, hold[r] - nnv, nnv);                         \
      hold[r] = h; hh[r] = h;                                                      \
    }                                                                              \
    uint2 wv;                                                                      \
    wv.x = pk2bf(hh[0], hh[1]);                                                    \
    wv.y = pk2bf(hh[2], hh[3]);                                                    \
    *(uint2*)(&ha[(P) ^ 1][col][doff]) = wv;                                       \
    pwv = wv;                                                                      \
    if ((T) < 126) {                 /* refill just-consumed register set */       \
      gq += pd * 192;                                                              \
      XR = *(const uint2*)(gq); XZ = *(const uint2*)(gq + 4); XN = *(const uint2*)(gq + 8); \
    }                                                                              \
    asm volatile("s_waitcnt lgkmcnt(0)" ::: "memory");                             \
    __builtin_amdgcn_s_barrier();                                                  \
  } while (0)

  for (int t = 0; t < 128; t += 2) {
    SCAN_STEP(0, xra, xza, xna, t);
    SCAN_STEP(1, xrb, xzb, xnb, t + 1);
  }
  *(uint2*)hq = pwv;   // h(127)
  #undef SCAN_STEP
}

// ---------------------------------------------------------------------------
// Kernel 3: out[b,c,h,w] = bo[c] + Wo[c,:] . (sum_dirs h)/4   (fp32 out)
// ---------------------------------------------------------------------------
__global__ __launch_bounds__(256) void k_out(const u16* __restrict__ Hall, const float* __restrict__ Wo,
                                             const float* __restrict__ bo, float* __restrict__ out){
  __shared__ u16 hs4[64][72];
  const int tid = threadIdx.x;
  const int wave = tid >> 6, lane = tid & 63;
  const int col = lane & 15, kq = lane >> 4;
  const long s0 = (long)blockIdx.x * 64;
  const int b   = (int)(s0 >> 14);
  const int hw0 = (int)(s0 & 16383);

  s8v bfrag[3][2]; f4v biasf[3];
  #pragma unroll
  for (int j = 0; j < 3; j++) {
    int g = wave * 48 + j * 16 + col;
    bfrag[j][0] = load8_f32_as_bf16(Wo + g * 64 + kq * 8);
    bfrag[j][1] = load8_f32_as_bf16(Wo + g * 64 + 32 + kq * 8);
    float bb = bo[g];
    biasf[j] = (f4v){bb, bb, bb, bb};
  }

  // Stage (sum of 4 direction h)/4 as bf16 — 16B loads per dir
  for (int idx = tid; idx < 64 * 8; idx += 256) {
    int sl = idx >> 3;
    int d8 = (idx & 7) * 8;
    long p = (s0 + sl) * 64 + d8;
    float s[8];
    {
      uint4 v = *(const uint4*)(Hall + p);
      const u16* pv = (const u16*)&v;
      #pragma unroll
      for (int i = 0; i < 8; i++) s[i] = bf2f(pv[i]);
    }
    #pragma unroll
    for (int dd = 1; dd < 4; dd++) {
      uint4 v = *(const uint4*)(Hall + dd * (NSp * 64) + p);
      const u16* pv = (const u16*)&v;
      #pragma unroll
      for (int i = 0; i < 8; i++) s[i] += bf2f(pv[i]);
    }
    uint2 w0, w1;
    w0.x = pk2bf(0.25f * s[0], 0.25f * s[1]);
    w0.y = pk2bf(0.25f * s[2], 0.25f * s[3]);
    w1.x = pk2bf(0.25f * s[4], 0.25f * s[5]);
    w1.y = pk2bf(0.25f * s[6], 0.25f * s[7]);
    *(uint2*)(&hs4[sl][d8]) = w0;
    *(uint2*)(&hs4[sl][d8 + 4]) = w1;
  }
  __syncthreads();

  f4v acc[4][3];
  #pragma unroll
  for (int m = 0; m < 4; m++)
    #pragma unroll
    for (int j = 0; j < 3; j++) acc[m][j] = biasf[j];

  #pragma unroll
  for (int kc = 0; kc < 2; kc++) {
    #pragma unroll
    for (int m = 0; m < 4; m++) {
      s8v a = *(const s8v*)(&hs4[m * 16 + col][kc * 32 + kq * 8]);
      #pragma unroll
      for (int j = 0; j < 3; j++)
        acc[m][j] = __builtin_amdgcn_mfma_f32_16x16x32_bf16(a, bfrag[j][kc], acc[m][j], 0, 0, 0);
    }
  }

  #pragma unroll
  for (int j = 0; j < 3; j++) {
    int g = wave * 48 + j * 16 + col;
    #pragma unroll
    for (int m = 0; m < 4; m++) {
      float4 v;
      v.x = acc[m][j][0]; v.y = acc[m][j][1];
      v.z = acc[m][j][2]; v.w = acc[m][j][3];
      long addr = ((long)(b * 192 + g) << 14) + hw0 + m * 16 + kq * 4;
      *(float4*)(out + addr) = v;
    }
  }
}

// ---------------------------------------------------------------------------
extern "C" void kernel_launch(void* const* d_in, const int* in_sizes, int n_in,
                              void* d_out, int out_size, void* d_ws, size_t ws_size,
                              hipStream_t stream){
  const float* x    = (const float*)d_in[0];
  const float* Wi   = (const float*)d_in[1];
  const float* bi   = (const float*)d_in[2];
  const float* W_ih = (const float*)d_in[3];
  const float* W_hh = (const float*)d_in[4];
  const float* b_ih = (const float*)d_in[5];
  const float* b_hh = (const float*)d_in[6];
  const float* Wo   = (const float*)d_in[7];
  const float* bo   = (const float*)d_in[8];

  char* ws = (char*)d_ws;
  u16*   wcomb = (u16*)(ws);                       // 192*192 bf16        = 73728 B
  float* bcomb = (float*)(ws + 73728);             // 192 fp32            = 768 B
  u16*   G     = (u16*)(ws + 74496);               // 131072*192 bf16     = 50331648 B
  u16*   Hall  = (u16*)(ws + 50406144);            // 4*131072*64 bf16    = 67108864 B
                                                   // total               = 117515008 B

  k_wcomb<<<145,  256, 0, stream>>>(Wi, bi, W_ih, b_ih, b_hh, wcomb, bcomb);
  k_gates<<<2048, 256, 0, stream>>>(x, wcomb, bcomb, G);
  k_scan <<<256,  256, 0, stream>>>(G, W_hh, b_hh, Hall);
  k_out  <<<2048, 256, 0, stream>>>(Hall, Wo, bo, (float*)d_out);
}

// Round 7
// 289.813 us; speedup vs baseline: 1.1383x; 1.1383x over previous
//
#include <hip/hip_runtime.h>

// Problem constants
#define Cn   192      // channels = 3*D
#define Dn   64       // hidden
#define G3   192      // 3*D gates
#define HWn  16384    // H*W per batch
#define NSp  131072L  // B*H*W total spatial
#define Tn   128

typedef unsigned short u16;
typedef __attribute__((ext_vector_type(8))) short s8v;   // 8 bf16 (4 VGPRs) MFMA A/B frag
typedef __attribute__((ext_vector_type(4))) float f4v;   // MFMA C/D frag

__device__ __forceinline__ float bf2f(u16 u){
  union { unsigned int i; float f; } v; v.i = ((unsigned int)u) << 16; return v.f;
}
__device__ __forceinline__ u16 f2bf(float f){
  union { float f; unsigned int u; } v; v.f = f;
  return (u16)((v.u + 0x7FFFu + ((v.u >> 16) & 1u)) >> 16);  // RNE
}
__device__ __forceinline__ s8v load8_f32_as_bf16(const float* __restrict__ p){
  s8v r;
  #pragma unroll
  for (int i = 0; i < 8; i++) r[i] = (short)f2bf(p[i]);
  return r;
}
// fast transcendentals
__device__ __forceinline__ float ex2f(float x){
#if __has_builtin(__builtin_amdgcn_exp2f)
  return __builtin_amdgcn_exp2f(x);
#else
  float r; asm("v_exp_f32 %0, %1" : "=v"(r) : "v"(x)); return r;
#endif
}
__device__ __forceinline__ float rcpa(float x){
#if __has_builtin(__builtin_amdgcn_rcpf)
  return __builtin_amdgcn_rcpf(x);
#else
  float r; asm("v_rcp_f32 %0, %1" : "=v"(r) : "v"(x)); return r;
#endif
}
__device__ __forceinline__ unsigned int pk2bf(float a, float b){
  unsigned int r; asm("v_cvt_pk_bf16_f32 %0, %1, %2" : "=v"(r) : "v"(a), "v"(b)); return r;
}

// gate-group scale folded into weights: r,z: -log2(e)  (sigmoid(x)=rcp(1+exp2(-log2e*x)))
//                                       n:   -2log2(e) (tanh(y)=2*rcp(1+exp2(-2log2e*y))-1)
#define SC_RZ (-1.4426950408889634f)
#define SC_N  (-2.8853900817779268f)

// G layout (interleaved for scan locality): per spatial s, 16 d-quads x 3 gate
// groups x 4: element offset = s*192 + dq*12 + g3*4 + r, where d = 4*dq + r.

// ---------------------------------------------------------------------------
// Kernel 0: W_comb = W_ih @ Wi (bf16, gate-scaled); b_comb = W_ih@bi + b_ih
// (+ b_hh for r,z gates — n's b_hh sits inside r*(.) and cannot fold), scaled.
// ---------------------------------------------------------------------------
__global__ __launch_bounds__(256) void k_wcomb(const float* __restrict__ Wi, const float* __restrict__ bi,
                                               const float* __restrict__ W_ih, const float* __restrict__ b_ih,
                                               const float* __restrict__ b_hh,
                                               u16* __restrict__ wcomb, float* __restrict__ bcomb){
  if (blockIdx.x < 144) {
    int idx = blockIdx.x * 256 + threadIdx.x;   // 36864 = 192*192
    int g = idx / 192, c = idx - g * 192;
    float acc = 0.f;
    #pragma unroll 8
    for (int d = 0; d < 64; d++)
      acc += W_ih[g * 64 + d] * Wi[d * 192 + c];
    float sc = (g >= 128) ? SC_N : SC_RZ;
    wcomb[g * 192 + c] = f2bf(sc * acc);
  } else if (threadIdx.x < 192) {
    int g = threadIdx.x;
    float acc = b_ih[g];
    for (int d = 0; d < 64; d++)
      acc += W_ih[g * 64 + d] * bi[d];
    if (g < 128) acc += b_hh[g];          // fold r,z hidden-bias into the x-gate stream
    float sc = (g >= 128) ? SC_N : SC_RZ;
    bcomb[g] = sc * acc;
  }
}

// ---------------------------------------------------------------------------
// Kernel 1: G = x @ W_comb^T + b_comb  (bf16, pre-scaled, interleaved layout).
// Staging: 4ch x 4sp per thread, cvt_pk pack, ds_write_b64 with an 8-channel
// XOR swizzle (c ^= ((s>>2)&3)<<3); read applies the same XOR (involution).
// ---------------------------------------------------------------------------
__global__ __launch_bounds__(256) void k_gates(const float* __restrict__ x, const u16* __restrict__ wcomb,
                                               const float* __restrict__ bcomb, u16* __restrict__ G){
  __shared__ u16 xT[64][200];                 // [spatial][channel], row 400 B
  const int tid = threadIdx.x;
  const int wave = tid >> 6, lane = tid & 63;
  const int col = lane & 15, kq = lane >> 4;
  const long s0 = (long)blockIdx.x * 64;
  const int b   = (int)(s0 >> 14);
  const int hw0 = (int)(s0 & 16383);
  const int dq  = 4 * wave + kq;              // this lane's d-quad (d = 4dq..4dq+3)
  const int cswz = (col >> 2) << 3;           // read-side XOR

  // A-frags: gate rows g = g3*64 + 16*wave + col; k = kc*32 + kq*8 + i
  s8v afrag[3][6];
  f4v biasv[3];
  #pragma unroll
  for (int g3 = 0; g3 < 3; g3++) {
    int g = g3 * 64 + 16 * wave + col;
    #pragma unroll
    for (int kc = 0; kc < 6; kc++)
      afrag[g3][kc] = *(const s8v*)(wcomb + g * 192 + kc * 32 + kq * 8);
    biasv[g3] = *(const f4v*)(bcomb + g3 * 64 + 16 * wave + 4 * kq);
  }

  // Stage x tile transposed: 4 channels x 4 spatial per work item
  const float* xb = x + (long)b * 192 * HWn + hw0;
  for (int idx = tid; idx < 768; idx += 256) {
    int c  = (idx >> 4) * 4;
    int s4 = (idx & 15) * 4;
    f4v v0 = *(const f4v*)(xb + (long)(c + 0) * HWn + s4);
    f4v v1 = *(const f4v*)(xb + (long)(c + 1) * HWn + s4);
    f4v v2 = *(const f4v*)(xb + (long)(c + 2) * HWn + s4);
    f4v v3 = *(const f4v*)(xb + (long)(c + 3) * HWn + s4);
    #pragma unroll
    for (int j = 0; j < 4; j++) {
      int s  = s4 + j;
      int cS = c ^ (((s >> 2) & 3) << 3);
      uint2 wv;
      wv.x = pk2bf(v0[j], v1[j]);
      wv.y = pk2bf(v2[j], v3[j]);
      *(uint2*)(&xT[s][cS]) = wv;
    }
  }
  __syncthreads();

  f4v acc[4][3];
  #pragma unroll
  for (int nt = 0; nt < 4; nt++)
    #pragma unroll
    for (int g3 = 0; g3 < 3; g3++) acc[nt][g3] = biasv[g3];

  #pragma unroll
  for (int kc = 0; kc < 6; kc++) {
    #pragma unroll
    for (int nt = 0; nt < 4; nt++) {
      s8v bx = *(const s8v*)(&xT[nt * 16 + col][(kc * 32 + kq * 8) ^ cswz]);
      #pragma unroll
      for (int g3 = 0; g3 < 3; g3++)
        acc[nt][g3] = __builtin_amdgcn_mfma_f32_16x16x32_bf16(afrag[g3][kc], bx, acc[nt][g3], 0, 0, 0);
    }
  }

  // Epilogue: D rows = gates (4kq+r within tile), col = spatial -> uint2 stores
  #pragma unroll
  for (int nt = 0; nt < 4; nt++) {
    long sRow = (s0 + nt * 16 + col) * 192 + dq * 12;
    #pragma unroll
    for (int g3 = 0; g3 < 3; g3++) {
      uint2 wv;
      wv.x = pk2bf(acc[nt][g3][0], acc[nt][g3][1]);
      wv.y = pk2bf(acc[nt][g3][2], acc[nt][g3][3]);
      *(uint2*)(G + sRow + g3 * 4) = wv;
    }
  }
}

// ---------------------------------------------------------------------------
// Kernel 2: directional GRU scans — round-4 proven structure (prefetch-at-top
// depth-2, rotate movs, tail Hall store, lgkmcnt-only raw barrier +
// sched_barrier(0) anchor, dynamic buffer index). Single change vs round 4:
// merged z/n reciprocal in the gate body (5 trans/h instead of 6).
// ---------------------------------------------------------------------------
__global__ __launch_bounds__(256) void k_scan(const u16* __restrict__ G, const float* __restrict__ W_hh,
                                              const float* __restrict__ b_hh, u16* __restrict__ Hall){
  __shared__ u16 ha[2][16][72];   // [buf][seq][d], row 144 B (16B-aligned)
  const int tid = threadIdx.x;
  const int w = tid >> 6, lane = tid & 63;
  const int col = lane & 15, kq = lane >> 4;
  const int dir  = blockIdx.x >> 6;   // 0:right 1:down 2:left 3:up
  const int sblk = blockIdx.x & 63;
  const int doff = 16 * w + 4 * kq;   // this lane's 4 d values
  const int dq   = 4 * w + kq;

  // A-frags: W_hh rows g = g3*64 + 16w + col, standard k order, gate-scaled
  s8v afrag[3][2];
  #pragma unroll
  for (int g3 = 0; g3 < 3; g3++) {
    float sc = (g3 == 2) ? SC_N : SC_RZ;
    const float* wr = W_hh + (g3 * 64 + 16 * w + col) * 64;
    #pragma unroll
    for (int kc = 0; kc < 2; kc++) {
      s8v f;
      #pragma unroll
      for (int i = 0; i < 8; i++) f[i] = (short)f2bf(sc * wr[kc * 32 + kq * 8 + i]);
      afrag[g3][kc] = f;
    }
  }
  // n-gate hidden bias in accumulator init (r,z b_hh folded into G)
  f4v biasn;
  {
    const float* bb = b_hh + 128 + doff;
    biasn = (f4v){SC_N * bb[0], SC_N * bb[1], SC_N * bb[2], SC_N * bb[3]};
  }

  const int seq = sblk * 16 + col;             // 0..1023
  const int b = seq >> 7, a = seq & 127;
  long base; int stride;
  if ((dir & 1) == 0) { base = ((long)(b * 128 + a)) * 128; stride = 1;   } // scan over w
  else                { base = (long)b * 16384 + a;         stride = 128; } // scan over h
  const int rev = dir >> 1;
  const long pd = rev ? -(long)stride : (long)stride;
  u16* __restrict__ Hs = Hall + (long)dir * (NSp * 64);
  const long pos0 = base + (long)(rev ? 127 : 0) * stride;
  const u16* gq = G  + pos0 * 192 + dq * 12;   // 24B contiguous (r,z,n) triple
  u16*       hq = Hs + pos0 * 64  + doff;

  for (int i = tid; i < 2 * 16 * 72; i += 256) ((u16*)ha)[i] = 0;   // h0 = 0

  float hold[4] = {0.f, 0.f, 0.f, 0.f};

  // depth-2 G prefetch: t=0 and t=1 in flight before the loop
  uint2 xr0, xz0, xn0, xr1, xz1, xn1;
  xr0 = *(const uint2*)(gq); xz0 = *(const uint2*)(gq + 4); xn0 = *(const uint2*)(gq + 8);
  gq += pd * 192;
  xr1 = *(const uint2*)(gq); xz1 = *(const uint2*)(gq + 4); xn1 = *(const uint2*)(gq + 8);
  __syncthreads();   // one full drain, before the loop only

  int p = 0;
  for (int t = 0; t < 128; t++) {
    // issue prefetch for t+2 (~2 steps of latency slack)
    uint2 nxr, nxz, nxn;
    if (t < 126) {
      gq += pd * 192;
      nxr = *(const uint2*)(gq); nxz = *(const uint2*)(gq + 4); nxn = *(const uint2*)(gq + 8);
    }

    // B-frags (n=col=seq): two b128 reads, standard contiguous layout
    s8v u0 = *(const s8v*)(&ha[p][col][kq * 8]);
    s8v u1 = *(const s8v*)(&ha[p][col][32 + kq * 8]);

    f4v acc0 = (f4v){0.f, 0.f, 0.f, 0.f};
    f4v acc1 = (f4v){0.f, 0.f, 0.f, 0.f};
    f4v acc2 = biasn;
    acc0 = __builtin_amdgcn_mfma_f32_16x16x32_bf16(afrag[0][0], u0, acc0, 0, 0, 0);
    acc1 = __builtin_amdgcn_mfma_f32_16x16x32_bf16(afrag[1][0], u0, acc1, 0, 0, 0);
    acc2 = __builtin_amdgcn_mfma_f32_16x16x32_bf16(afrag[2][0], u0, acc2, 0, 0, 0);
    acc0 = __builtin_amdgcn_mfma_f32_16x16x32_bf16(afrag[0][1], u1, acc0, 0, 0, 0);
    acc1 = __builtin_amdgcn_mfma_f32_16x16x32_bf16(afrag[1][1], u1, acc1, 0, 0, 0);
    acc2 = __builtin_amdgcn_mfma_f32_16x16x32_bf16(afrag[2][1], u1, acc2, 0, 0, 0);

    // gate phase — lane-local (gates g3*64 + doff + r, seq = col)
    const u16* pxr = (const u16*)&xr0;
    const u16* pxz = (const u16*)&xz0;
    const u16* pxn = (const u16*)&xn0;
    float hh[4];
    #pragma unroll
    for (int r = 0; r < 4; r++) {
      float erv = ex2f(bf2f(pxr[r]) + acc0[r]);
      float rrv = rcpa(1.f + erv);
      float ezv = ex2f(bf2f(pxz[r]) + acc1[r]);
      float dzv = 1.f + ezv;
      float env = ex2f(bf2f(pxn[r]) + rrv * acc2[r]);
      float dnv = 1.f + env;
      float qv  = rcpa(dzv * dnv);      // merged z,n reciprocal
      float zzv = qv * dnv;             // = 1/(1+ezv)  (sigmoid)
      float nnv = __builtin_fmaf(dzv + dzv, qv, -1.f);  // = 2/(1+env)-1 (tanh)
      float h   = __builtin_fmaf(zzv, hold[r] - nnv, nnv);
      hold[r] = h; hh[r] = h;
    }
    uint2 wv;
    wv.x = pk2bf(hh[0], hh[1]);
    wv.y = pk2bf(hh[2], hh[3]);
    *(uint2*)(&ha[p ^ 1][col][doff]) = wv;   // h for next step (other buffer)
    *(uint2*)(hq) = wv;                      // stream h out (never waited on)
    hq += pd * 64;

    // rotate prefetch pipeline
    xr0 = xr1; xz0 = xz1; xn0 = xn1;
    if (t < 126) { xr1 = nxr; xz1 = nxz; xn1 = nxn; }

    // raw barrier: drain LDS only; global loads/stores stay in flight
    asm volatile("s_waitcnt lgkmcnt(0)" ::: "memory");
    __builtin_amdgcn_s_barrier();
    __builtin_amdgcn_sched_barrier(0);
    p ^= 1;
  }
}

// ---------------------------------------------------------------------------
// Kernel 3: out[b,c,h,w] = bo[c] + Wo[c,:] . (sum_dirs h)/4   (fp32 out)
// ---------------------------------------------------------------------------
__global__ __launch_bounds__(256) void k_out(const u16* __restrict__ Hall, const float* __restrict__ Wo,
                                             const float* __restrict__ bo, float* __restrict__ out){
  __shared__ u16 hs4[64][72];
  const int tid = threadIdx.x;
  const int wave = tid >> 6, lane = tid & 63;
  const int col = lane & 15, kq = lane >> 4;
  const long s0 = (long)blockIdx.x * 64;
  const int b   = (int)(s0 >> 14);
  const int hw0 = (int)(s0 & 16383);

  s8v bfrag[3][2]; f4v biasf[3];
  #pragma unroll
  for (int j = 0; j < 3; j++) {
    int g = wave * 48 + j * 16 + col;
    bfrag[j][0] = load8_f32_as_bf16(Wo + g * 64 + kq * 8);
    bfrag[j][1] = load8_f32_as_bf16(Wo + g * 64 + 32 + kq * 8);
    float bb = bo[g];
    biasf[j] = (f4v){bb, bb, bb, bb};
  }

  // Stage (sum of 4 direction h)/4 as bf16 — 16B loads per dir
  for (int idx = tid; idx < 64 * 8; idx += 256) {
    int sl = idx >> 3;
    int d8 = (idx & 7) * 8;
    long p = (s0 + sl) * 64 + d8;
    float s[8];
    {
      uint4 v = *(const uint4*)(Hall + p);
      const u16* pv = (const u16*)&v;
      #pragma unroll
      for (int i = 0; i < 8; i++) s[i] = bf2f(pv[i]);
    }
    #pragma unroll
    for (int dd = 1; dd < 4; dd++) {
      uint4 v = *(const uint4*)(Hall + dd * (NSp * 64) + p);
      const u16* pv = (const u16*)&v;
      #pragma unroll
      for (int i = 0; i < 8; i++) s[i] += bf2f(pv[i]);
    }
    uint2 w0, w1;
    w0.x = pk2bf(0.25f * s[0], 0.25f * s[1]);
    w0.y = pk2bf(0.25f * s[2], 0.25f * s[3]);
    w1.x = pk2bf(0.25f * s[4], 0.25f * s[5]);
    w1.y = pk2bf(0.25f * s[6], 0.25f * s[7]);
    *(uint2*)(&hs4[sl][d8]) = w0;
    *(uint2*)(&hs4[sl][d8 + 4]) = w1;
  }
  __syncthreads();

  f4v acc[4][3];
  #pragma unroll
  for (int m = 0; m < 4; m++)
    #pragma unroll
    for (int j = 0; j < 3; j++) acc[m][j] = biasf[j];

  #pragma unroll
  for (int kc = 0; kc < 2; kc++) {
    #pragma unroll
    for (int m = 0; m < 4; m++) {
      s8v a = *(const s8v*)(&hs4[m * 16 + col][kc * 32 + kq * 8]);
      #pragma unroll
      for (int j = 0; j < 3; j++)
        acc[m][j] = __builtin_amdgcn_mfma_f32_16x16x32_bf16(a, bfrag[j][kc], acc[m][j], 0, 0, 0);
    }
  }

  #pragma unroll
  for (int j = 0; j < 3; j++) {
    int g = wave * 48 + j * 16 + col;
    #pragma unroll
    for (int m = 0; m < 4; m++) {
      float4 v;
      v.x = acc[m][j][0]; v.y = acc[m][j][1];
      v.z = acc[m][j][2]; v.w = acc[m][j][3];
      long addr = ((long)(b * 192 + g) << 14) + hw0 + m * 16 + kq * 4;
      *(float4*)(out + addr) = v;
    }
  }
}

// ---------------------------------------------------------------------------
extern "C" void kernel_launch(void* const* d_in, const int* in_sizes, int n_in,
                              void* d_out, int out_size, void* d_ws, size_t ws_size,
                              hipStream_t stream){
  const float* x    = (const float*)d_in[0];
  const float* Wi   = (const float*)d_in[1];
  const float* bi   = (const float*)d_in[2];
  const float* W_ih = (const float*)d_in[3];
  const float* W_hh = (const float*)d_in[4];
  const float* b_ih = (const float*)d_in[5];
  const float* b_hh = (const float*)d_in[6];
  const float* Wo   = (const float*)d_in[7];
  const float* bo   = (const float*)d_in[8];

  char* ws = (char*)d_ws;
  u16*   wcomb = (u16*)(ws);                       // 192*192 bf16        = 73728 B
  float* bcomb = (float*)(ws + 73728);             // 192 fp32            = 768 B
  u16*   G     = (u16*)(ws + 74496);               // 131072*192 bf16     = 50331648 B
  u16*   Hall  = (u16*)(ws + 50406144);            // 4*131072*64 bf16    = 67108864 B
                                                   // total               = 117515008 B

  k_wcomb<<<145,  256, 0, stream>>>(Wi, bi, W_ih, b_ih, b_hh, wcomb, bcomb);
  k_gates<<<2048, 256, 0, stream>>>(x, wcomb, bcomb, G);
  k_scan <<<256,  256, 0, stream>>>(G, W_hh, b_hh, Hall);
  k_out  <<<2048, 256, 0, stream>>>(Hall, Wo, bo, (float*)d_out);
}